// Round 9
// baseline (676.025 us; speedup 1.0000x reference)
//
#include <hip/hip_runtime.h>
#include <stdint.h>

// Problem constants (B=256, L=2048, H=64, TE=64)
#define NB 256
#define NL 2048

typedef __attribute__((ext_vector_type(8))) short short8;
typedef __attribute__((ext_vector_type(4))) float f32x4;
#define MFMA16(a,b,c) __builtin_amdgcn_mfma_f32_16x16x32_bf16(a,b,c,0,0,0)

// ---------- bf16 helpers ----------
// R16: inp bf16 intermediate, gates in scan (371->334).
// R17: full-fusion spill (484). R18/19: wave-split weights, 317 total.
// R20: launch_bounds(512,4) => compiler chose VGPR=64 => spill => 726.
// R21: 512thr no hint => VGPR 124 clean, but 1 WG/CU at 75KB LDS. 323.
// R22: 1024thr no hint => compiler AGAIN chose VGPR=64 (targets 8
//      waves/EU ignoring the working set) => spill => 661.
//      Occupancy DID hit 46% — only regalloc is wrong.
// R23: R22 + amdgpu_waves_per_eu(4,4): pin 4 waves/SIMD => VGPR budget
//      128; working set ~124 fits (proven at 512thr in R21).
static __device__ __forceinline__ unsigned short f2bf(float f) {
    union { float f; uint32_t u; } v; v.f = f;
    uint32_t u = v.u;
    uint32_t r = u + 0x7fffu + ((u >> 16) & 1u);
    return (unsigned short)(r >> 16);
}
static __device__ __forceinline__ float bflo(uint32_t u) {
    union { uint32_t u; float f; } v; v.u = u << 16; return v.f;
}
static __device__ __forceinline__ float bfhi(uint32_t u) {
    union { uint32_t u; float f; } v; v.u = u & 0xffff0000u; return v.f;
}
#if __has_builtin(__builtin_amdgcn_cvt_pk_bf16_f32)
typedef __attribute__((ext_vector_type(2))) __bf16 bf16x2_t;
static __device__ __forceinline__ uint32_t pk2(float lo, float hi) {
    union { bf16x2_t v; uint32_t u; } c;
    c.v = __builtin_amdgcn_cvt_pk_bf16_f32(lo, hi);
    return c.u;
}
static __device__ __forceinline__ unsigned short bf1(float v) {
    union { bf16x2_t v; uint32_t u; } c;
    c.v = __builtin_amdgcn_cvt_pk_bf16_f32(v, v);
    return (unsigned short)(c.u & 0xffffu);
}
#else
static __device__ __forceinline__ uint32_t pk2(float lo, float hi) {
    return ((uint32_t)f2bf(hi) << 16) | (uint32_t)f2bf(lo);
}
static __device__ __forceinline__ unsigned short bf1(float v) { return f2bf(v); }
#endif
static __device__ __forceinline__ short8 frag8(const float* p) {
    short8 r;
#pragma unroll
    for (int j = 0; j < 8; ++j) r[j] = (short)f2bf(p[j]);
    return r;
}

// LDS-only barrier: global stores/loads stay in flight across it.
static __device__ __forceinline__ void barrier_lds() {
    asm volatile("s_waitcnt lgkmcnt(0)" ::: "memory");
    __builtin_amdgcn_s_barrier();
}

// =====================================================================
// kernel 1: fused inp-gen + gates + chunked scan, BOTH dirs per block.
// 1024 thr = 16 waves; dir = tid>>9; within a dir-half: 8 waves, lane=h,
// wave q owns 16-l chunk; gen-GEMM wave (mq=q>>1, nh=q&1) owns 2 m-tiles
// x 2 n-tiles. Pipeline per segment (3 barriers):
//   alpha { OUT(i-1) | GATES(i) }
//   beta  { t-load(i+1) | scanAB(i) | G1(i+1) [te1 from s_wb] }
//   gamma { x-load(i+1) | carry(i) | G2(i+1) }
// All fragment orders/roundings identical to R16 -> bitwise-identical h.
// =====================================================================
#define SSTR 129

__global__ __launch_bounds__(1024)
__attribute__((amdgpu_waves_per_eu(4, 4)))
void scan_fused(
    const float* __restrict__ x, const float* __restrict__ t,
    const float* __restrict__ mtok,
    const float* __restrict__ te_w1, const float* __restrict__ te_b1,
    const float* __restrict__ te_w2, const float* __restrict__ te_b2,
    const float* __restrict__ fpw, const float* __restrict__ fpb,
    const float* __restrict__ bpw, const float* __restrict__ bpb,
    const float* __restrict__ fwz, const float* __restrict__ fbz,
    const float* __restrict__ fwh, const float* __restrict__ fbh,
    const float* __restrict__ bwz, const float* __restrict__ bbz,
    const float* __restrict__ bwh, const float* __restrict__ bbh,
    int b0,
    unsigned short* __restrict__ hf, unsigned short* __restrict__ hb)
{
    __shared__ __align__(16) unsigned short s_tenc[2][128*72]; // 36864 B
    __shared__ __align__(16) unsigned short s_inp[2][128*72];  // 36864 B
    __shared__ uint32_t s_seg[2][64*SSTR];                     // 66048 B
    __shared__ float s_A[2][8][65], s_B[2][8][65];             //  8320 B
    __shared__ float s_H[2][64];                               //   512 B
    __shared__ float2 s_wb[64];                                //   512 B
    // total 149120 B (145.6 KB) -> single WG, 16 waves/CU

    const int rl   = blockIdx.x;
    const int tid  = threadIdx.x;
    const int dir  = tid >> 9;    // 0 fwd, 1 bwd
    const int tid9 = tid & 511;
    const int h    = tid9 & 63;   // lane
    const int q    = tid9 >> 6;   // wave-in-half 0..7
    const int lq   = h >> 4;
    const int ln   = h & 15;
    const int mq   = q >> 1;      // m-tile pair owner (0..3)
    const int nh   = q & 1;       // n-tile pair owner (0..1)

    const int gx = (b0 + rl) << 11;     // global l base for this b
    unsigned short* out = (dir ? hb : hf) + (size_t)rl * NL * 64;

    unsigned short* tenc = s_tenc[dir];
    unsigned short* inp  = s_inp[dir];
    uint32_t*       seg  = s_seg[dir];

    // ---- weights (persistent regs, nt-split: this wave's 2 n-tiles) ----
    short8 bte[2][2];
    float bite[2];
#pragma unroll
    for (int ni = 0; ni < 2; ++ni) {
        const int nt = nh*2 + ni;
        const float* row = te_w2 + (nt*16 + ln)*64;
#pragma unroll
        for (int ks = 0; ks < 2; ++ks) bte[ni][ks] = frag8(row + lq*8 + ks*32);
        bite[ni] = te_b2[nt*16 + ln];
    }
    const float* PW = dir ? bpw : fpw;
    const float* PB = dir ? bpb : fpb;
    short8 bpj[2][3];
    float bipj[2];
#pragma unroll
    for (int ni = 0; ni < 2; ++ni) {
        const int nt = nh*2 + ni;
        const float* row = PW + (nt*16 + ln)*67;
#pragma unroll
        for (int ks = 0; ks < 2; ++ks) {
            float tmp[8];
#pragma unroll
            for (int j = 0; j < 8; ++j) tmp[j] = row[3 + lq*8 + ks*32 + j];
            bpj[ni][ks] = frag8(tmp);
        }
        {
            float tmp[8];
#pragma unroll
            for (int j = 0; j < 8; ++j) tmp[j] = (lq == 0 && j < 3) ? row[j] : 0.f;
            bpj[ni][2] = frag8(tmp);
        }
        bipj[ni] = PB[nt*16 + ln];
    }
    const float* WZ = dir ? bwz : fwz;
    const float* WH = dir ? bwh : fwh;
    const float* BZ = dir ? bbz : fbz;
    const float* BH = dir ? bbh : fbh;
    short8 bz[2][2], bh[2][2];
    float biz[2], bih[2];
#pragma unroll
    for (int ni = 0; ni < 2; ++ni) {
        const int nt = nh*2 + ni;
        const float* rz = WZ + (nt*16 + ln)*64;
        const float* rh = WH + (nt*16 + ln)*64;
#pragma unroll
        for (int ks = 0; ks < 2; ++ks) {
            bz[ni][ks] = frag8(rz + lq*8 + ks*32);
            bh[ni][ks] = frag8(rh + lq*8 + ks*32);
        }
        biz[ni] = BZ[nt*16 + ln];
        bih[ni] = BH[nt*16 + ln];
    }
    const float mt0 = mtok[0], mt1 = mtok[1];

    // ---- phase lambdas ----
    auto G1 = [&](const float* tvv) {  // te1 from s_wb -> tenc GEMM
#pragma unroll
        for (int mi = 0; mi < 2; ++mi) {
            short8 a0, a1;
#pragma unroll
            for (int j = 0; j < 8; ++j) {
                const float2 wb0 = s_wb[lq*8 + j];
                const float2 wb1 = s_wb[lq*8 + 32 + j];
                a0[j] = (short)bf1(fmaxf(fmaf(tvv[mi], wb0.x, wb0.y), 0.f));
                a1[j] = (short)bf1(fmaxf(fmaf(tvv[mi], wb1.x, wb1.y), 0.f));
            }
#pragma unroll
            for (int ni = 0; ni < 2; ++ni) {
                f32x4 c = {0.f, 0.f, 0.f, 0.f};
                c = MFMA16(a0, bte[ni][0], c);
                c = MFMA16(a1, bte[ni][1], c);
                const int o = (nh*2+ni)*16 + ln;
#pragma unroll
                for (int r = 0; r < 4; ++r)
                    tenc[((mq*2+mi)*16 + lq*4 + r)*72 + o] = bf1(c[r] + bite[ni]);
            }
        }
    };
    auto G2 = [&](const float* xr0_, const float* xr1_, const float* xmc_) {
#pragma unroll
        for (int mi = 0; mi < 2; ++mi) {
            const int mrow = (mq*2+mi)*16 + ln;
            const short8 a0 = *(const short8*)(tenc + mrow*72 + lq*8);
            const short8 a1 = *(const short8*)(tenc + mrow*72 + lq*8 + 32);
            short8 a2 = {0,0,0,0,0,0,0,0};
            if (lq == 0) {
                const float mc  = xmc_[mi];
                const float x0m = (mc == 0.f) ? mt0 : xr0_[mi];
                const float x1m = (mc == 0.f) ? mt1 : xr1_[mi];
                a2[0] = (short)bf1(x0m);
                a2[1] = (short)bf1(x1m);
                a2[2] = (short)bf1(mc);
            }
#pragma unroll
            for (int ni = 0; ni < 2; ++ni) {
                f32x4 c = {0.f, 0.f, 0.f, 0.f};
                c = MFMA16(a0, bpj[ni][0], c);
                c = MFMA16(a1, bpj[ni][1], c);
                c = MFMA16(a2, bpj[ni][2], c);
                const int o = (nh*2+ni)*16 + ln;
#pragma unroll
                for (int r = 0; r < 4; ++r)
                    inp[((mq*2+mi)*16 + lq*4 + r)*72 + o] = bf1(c[r] + bipj[ni]);
            }
        }
    };
    auto GATES = [&]() {        // inp -> gates -> seg
#pragma unroll
        for (int mi = 0; mi < 2; ++mi) {
            const int mrow = (mq*2+mi)*16 + ln;
            const short8 a0 = *(const short8*)(inp + mrow*72 + lq*8);
            const short8 a1 = *(const short8*)(inp + mrow*72 + lq*8 + 32);
#pragma unroll
            for (int ni = 0; ni < 2; ++ni) {
                f32x4 cz  = {0.f, 0.f, 0.f, 0.f};
                f32x4 ch2 = {0.f, 0.f, 0.f, 0.f};
                cz  = MFMA16(a0, bz[ni][0], cz);
                cz  = MFMA16(a1, bz[ni][1], cz);
                ch2 = MFMA16(a0, bh[ni][0], ch2);
                ch2 = MFMA16(a1, bh[ni][1], ch2);
                const int hcol = (nh*2+ni)*16 + ln;
#pragma unroll
                for (int r = 0; r < 4; ++r) {
                    const float az = cz[r]  + biz[ni];
                    const float ah = ch2[r] + bih[ni];
                    const float z  = __builtin_amdgcn_rcpf(1.f + __expf(-az));
                    const float cc = fminf(fmaxf(ah, -15.f), 15.f);
                    const float e2 = __expf(2.f * cc);
                    const float th = 1.f - 2.f * __builtin_amdgcn_rcpf(e2 + 1.f);
                    seg[hcol*SSTR + (mq*2+mi)*16 + lq*4 + r] = pk2(1.f - z, z * th);
                }
            }
        }
    };

    if (tid9 < 64) s_H[dir][tid9] = 0.f;
    if (tid < 64)  s_wb[tid] = make_float2(te_w1[tid], te_b1[tid]);
    barrier_lds();              // s_wb visible to all waves

    // ---- prologue: fill pipeline for segment s0 ----
    const int s0 = dir ? 15 : 0;
    {
        float tv0[2];
#pragma unroll
        for (int mi = 0; mi < 2; ++mi)
            tv0[mi] = t[gx + s0*128 + (mq*2+mi)*16 + ln];
        G1(tv0);               // seg s0 -> tenc
    }
    barrier_lds();
    {
        float xr0_[2], xr1_[2], xmc_[2];
        if (lq == 0) {
#pragma unroll
            for (int mi = 0; mi < 2; ++mi) {
                const float* xp = x + (size_t)(gx + s0*128 + (mq*2+mi)*16 + ln)*3;
                xr0_[mi] = xp[0]; xr1_[mi] = xp[1]; xmc_[mi] = xp[2];
            }
        }
        G2(xr0_, xr1_, xmc_);  // seg s0 -> inp
    }
    barrier_lds();

    uint32_t regs[16];
    int l0p = 0;

#pragma unroll 1
    for (int si = 0; si < 16; ++si) {
        const int s = dir ? (15 - si) : si;
        const int sn = dir ? (14 - si) : (si + 1);   // next segment (if any)
        // ---- alpha: OUT(prev) + GATES(cur) ----
        if (si > 0) {
            float hv = s_A[dir][q][h];    // Hin written in-place by carry
#pragma unroll
            for (int i = 0; i < 16; ++i) {
                const int g = q*16 + i;
                const int xx = dir ? (127 - g) : g;
                out[(size_t)(l0p + xx)*64 + h] = bf1(hv);
                hv = fmaf(bflo(regs[i]), hv, bfhi(regs[i]));
            }
        }
        GATES();
        barrier_lds();
        // ---- beta: t-load(next) | scanAB(cur) | G1(next) ----
        float tvn[2];
        if (si < 15) {
#pragma unroll
            for (int mi = 0; mi < 2; ++mi)
                tvn[mi] = t[gx + sn*128 + (mq*2+mi)*16 + ln];
        }
        {
            float A = 1.f, Bc = 0.f;
#pragma unroll
            for (int i = 0; i < 16; ++i) {
                const int g = q*16 + i;
                const int xx = dir ? (127 - g) : g;
                const uint32_t uab = seg[h*SSTR + xx];
                regs[i] = uab;
                Bc = fmaf(bflo(uab), Bc, bfhi(uab));
                A *= bflo(uab);
            }
            s_A[dir][q][h] = A; s_B[dir][q][h] = Bc;
        }
        if (si < 15) G1(tvn);
        barrier_lds();
        // ---- gamma: x-load(next) | carry(cur) | G2(next) ----
        float xr0_[2], xr1_[2], xmc_[2];
        if (si < 15 && lq == 0) {
#pragma unroll
            for (int mi = 0; mi < 2; ++mi) {
                const float* xp = x + (size_t)(gx + sn*128 + (mq*2+mi)*16 + ln)*3;
                xr0_[mi] = xp[0]; xr1_[mi] = xp[1]; xmc_[mi] = xp[2];
            }
        }
        if (tid9 < 64) {
            float H = s_H[dir][tid9];
#pragma unroll
            for (int qq = 0; qq < 8; ++qq) {
                const float a = s_A[dir][qq][tid9], b = s_B[dir][qq][tid9];
                s_A[dir][qq][tid9] = H;    // in-place Hin
                H = fmaf(a, H, b);
            }
            s_H[dir][tid9] = H;
        }
        if (si < 15) G2(xr0_, xr1_, xmc_);
        barrier_lds();
        l0p = s * 128;
    }
    // ---- epilogue: OUT(last) ----
    {
        float hv = s_A[dir][q][h];
#pragma unroll
        for (int i = 0; i < 16; ++i) {
            const int g = q*16 + i;
            const int xx = dir ? (127 - g) : g;
            out[(size_t)(l0p + xx)*64 + h] = bf1(hv);
            hv = fmaf(bflo(regs[i]), hv, bfhi(regs[i]));
        }
    }
}

// =====================================================================
// kernel 2: MFMA head — unchanged from R15/R16.
// =====================================================================
__global__ __launch_bounds__(256, 3) void head_kernel(
    const float* __restrict__ x, const float* __restrict__ t,
    const float* __restrict__ te_w1, const float* __restrict__ te_b1,
    const float* __restrict__ te_w2, const float* __restrict__ te_b2,
    const unsigned short* __restrict__ hf, const unsigned short* __restrict__ hb,
    const float* __restrict__ w1, const float* __restrict__ b1,
    const float* __restrict__ w2, const float* __restrict__ b2,
    int b0,
    float* __restrict__ out)
{
    __shared__ __align__(16) unsigned short s_a[64*200];   // 25600 B
    __shared__ __align__(16) unsigned short s_te1[64*72];  //  9216 B
    __shared__ float s_part[4][64];                        //  1024 B
    __shared__ float s_mc[64];                             //   256 B

    const int tid = threadIdx.x;
    const int w   = tid >> 6;
    const int l   = tid & 63;
    const int lq  = l >> 4;
    const int ln  = l & 15;

    short8 bw1[2][6];
    float b1v[2], w2v[2];
#pragma unroll
    for (int p = 0; p < 2; ++p) {
        const int o = (2*w + p)*16 + ln;
        const float* row = w1 + o*192;
#pragma unroll
        for (int ks = 0; ks < 6; ++ks) bw1[p][ks] = frag8(row + lq*8 + ks*32);
        b1v[p] = b1[o];
        w2v[p] = w2[o];
    }
    short8 bte[2];
    {
        const float* row = te_w2 + (w*16 + ln)*64;
#pragma unroll
        for (int ks = 0; ks < 2; ++ks) bte[ks] = frag8(row + lq*8 + ks*32);
    }
    const float bias_te = te_b2[w*16 + ln];
    const float bias2 = b2[0];

    const int baseposl = blockIdx.x * 256;

    auto A = [&](int ch) {    // mc + te1 staging
        const int gbase = (b0 << 11) + baseposl + ch*64;
        if (tid < 64) s_mc[tid] = x[(size_t)(gbase + tid)*3 + 2];
        const int pos = tid & 63;
        const float tv = t[gbase + pos];
        const int k0 = (tid >> 6) * 16;
        uint32_t* dst = (uint32_t*)(s_te1 + pos*72 + k0);
#pragma unroll
        for (int kk = 0; kk < 16; kk += 2) {
            float v0 = fmaxf(fmaf(tv, te_w1[k0+kk],   te_b1[k0+kk]),   0.f);
            float v1 = fmaxf(fmaf(tv, te_w1[k0+kk+1], te_b1[k0+kk+1]), 0.f);
            dst[kk >> 1] = pk2(v0, v1);
        }
    };
    auto Bp = [&](int ch) {   // uint4 gather + tenc GEMM (disjoint s_a cols)
        const int chbase = baseposl + ch*64;
        const int ll0 = chbase & 2047;
        const int bl  = chbase >> 11;
        const size_t rowbase = (size_t)bl * NL * 64;
#pragma unroll
        for (int rep = 0; rep < 4; ++rep) {
            const int idx = rep*256 + tid;
            const int seg = idx >> 9;
            const int row = (idx >> 3) & 63;
            const int c   = idx & 7;
            const bool unm = s_mc[row] > 0.f;
            const uint4* src = (seg == 0)
                ? (const uint4*)(hf + rowbase + (size_t)(unm ? (ll0+row) : (NL-1))*64)
                : (const uint4*)(hb + rowbase + (size_t)(unm ? (ll0+row) : 0)*64);
            ((uint4*)s_a)[row*25 + seg*8 + c] = src[c];
        }
        const int o = w*16 + ln;
#pragma unroll
        for (int mt = 0; mt < 4; ++mt) {
            f32x4 c = {0.f, 0.f, 0.f, 0.f};
#pragma unroll
            for (int ks = 0; ks < 2; ++ks) {
                const short8 a = *(const short8*)(s_te1 + (mt*16+ln)*72 + lq*8 + ks*32);
                c = MFMA16(a, bte[ks], c);
            }
#pragma unroll
            for (int r = 0; r < 4; ++r) {
                const int m = mt*16 + lq*4 + r;
                s_a[m*200 + 128 + o] = bf1(c[r] + bias_te);
            }
        }
    };
    auto Cp = [&]() {         // GEMM1 + relu*w2 + quad shuffle-reduce
#pragma unroll
        for (int mt = 0; mt < 4; ++mt) {
            short8 af[6];
#pragma unroll
            for (int ks = 0; ks < 6; ++ks)
                af[ks] = *(const short8*)(s_a + (mt*16+ln)*200 + lq*8 + ks*32);
            float vs[4] = {0.f, 0.f, 0.f, 0.f};
#pragma unroll
            for (int p = 0; p < 2; ++p) {
                f32x4 c = {0.f, 0.f, 0.f, 0.f};
#pragma unroll
                for (int ks = 0; ks < 6; ++ks) c = MFMA16(af[ks], bw1[p][ks], c);
#pragma unroll
                for (int r = 0; r < 4; ++r)
                    vs[r] += fmaxf(c[r] + b1v[p], 0.f) * w2v[p];
            }
#pragma unroll
            for (int mask = 1; mask < 16; mask <<= 1) {
#pragma unroll
                for (int r = 0; r < 4; ++r)
                    vs[r] += __shfl_xor(vs[r], mask);
            }
            if (ln == 0) {
#pragma unroll
                for (int r = 0; r < 4; ++r)
                    s_part[w][mt*16 + lq*4 + r] = vs[r];
            }
        }
    };
    auto Dp = [&](int ch) {   // out write
        const int gbase = (b0 << 11) + baseposl + ch*64;
        if (tid < 64) {
            out[gbase + tid] = s_part[0][tid] + s_part[1][tid]
                             + s_part[2][tid] + s_part[3][tid] + bias2;
        }
    };

    A(0);
    barrier_lds();
#pragma unroll 1
    for (int ch = 0; ch < 4; ++ch) {
        Bp(ch);
        barrier_lds();
        Cp();
        barrier_lds();
        Dp(ch);                      // reads s_part
        if (ch < 3) A(ch + 1);       // writes s_mc/s_te1 — disjoint, overlapped
        barrier_lds();
    }
}

extern "C" void kernel_launch(void* const* d_in, const int* in_sizes, int n_in,
                              void* d_out, int out_size, void* d_ws, size_t ws_size,
                              hipStream_t stream)
{
    const float* x     = (const float*)d_in[0];
    const float* t     = (const float*)d_in[1];
    const float* mtok  = (const float*)d_in[2];
    const float* te_w1 = (const float*)d_in[3];
    const float* te_b1 = (const float*)d_in[4];
    const float* te_w2 = (const float*)d_in[5];
    const float* te_b2 = (const float*)d_in[6];
    const float* fpw   = (const float*)d_in[7];
    const float* fpb   = (const float*)d_in[8];
    const float* bpw   = (const float*)d_in[9];
    const float* bpb   = (const float*)d_in[10];
    const float* fwz   = (const float*)d_in[11];
    const float* fbz   = (const float*)d_in[12];
    const float* fwh   = (const float*)d_in[13];
    const float* fbh   = (const float*)d_in[14];
    const float* bwz   = (const float*)d_in[15];
    const float* bbz   = (const float*)d_in[16];
    const float* bwh   = (const float*)d_in[17];
    const float* bbh   = (const float*)d_in[18];
    const float* w1    = (const float*)d_in[19];
    const float* b1    = (const float*)d_in[20];
    const float* w2    = (const float*)d_in[21];
    const float* b2    = (const float*)d_in[22];

    // per b: h (2 dirs) = 512 KB
    const size_t per_b = 524288ull;
    int Bg = NB;
    while ((size_t)Bg * per_b > ws_size && Bg > 1) Bg >>= 1;
    const int nG = NB / Bg;

    char* ws = (char*)d_ws;
    unsigned short* hf = (unsigned short*)ws;
    unsigned short* hb = hf + (size_t)Bg * NL * 64;

    for (int g = 0; g < nG; ++g) {
        const int b0 = g * Bg;

        scan_fused<<<Bg, 1024, 0, stream>>>(
            x, t, mtok, te_w1, te_b1, te_w2, te_b2,
            fpw, fpb, bpw, bpb, fwz, fbz, fwh, fbh, bwz, bbz, bwh, bbh,
            b0, hf, hb);

        head_kernel<<<8 * Bg, 256, 0, stream>>>(
            x, t, te_w1, te_b1, te_w2, te_b2,
            hf, hb, w1, b1, w2, b2, b0, (float*)d_out);
    }
}

// Round 10
// 336.254 us; speedup vs baseline: 2.0105x; 2.0105x over previous
//
#include <hip/hip_runtime.h>
#include <stdint.h>

// Problem constants (B=256, L=2048, H=64, TE=64)
#define NB 256
#define NL 2048

typedef __attribute__((ext_vector_type(8))) short short8;
typedef __attribute__((ext_vector_type(4))) float f32x4;
#define MFMA16(a,b,c) __builtin_amdgcn_mfma_f32_16x16x32_bf16(a,b,c,0,0,0)

// ---------- bf16 helpers ----------
// R16: inp bf16 intermediate, gates in scan (371->334).
// R17: full-fusion spill (484). R18/19: wave-split weights, 317 total.
// R20/R22/R23: every attempt to raise scan occupancy (launch_bounds 2nd
//      arg, 1024-thr WG, waves_per_eu) made hipcc pin VGPR=64 => spill
//      (726/661/676). CLOSED: scan stays at the R21 shape — 512 thr,
//      no hints, VGPR 124, 75.3KB LDS, ~168us.
// R24: head_kernel overhaul (math unchanged): (a) T14 async gather —
//      issue next chunk's uint4 loads during Cp's MFMA, ds_write next
//      phase; (b) te1 in-register via s_wb table (s_te1 + one barrier
//      phase removed); (c) mc hoisted to prologue (s_mcall). LDS
//      36.4->28.2KB, 2 barriers/chunk.
static __device__ __forceinline__ unsigned short f2bf(float f) {
    union { float f; uint32_t u; } v; v.f = f;
    uint32_t u = v.u;
    uint32_t r = u + 0x7fffu + ((u >> 16) & 1u);
    return (unsigned short)(r >> 16);
}
static __device__ __forceinline__ float bflo(uint32_t u) {
    union { uint32_t u; float f; } v; v.u = u << 16; return v.f;
}
static __device__ __forceinline__ float bfhi(uint32_t u) {
    union { uint32_t u; float f; } v; v.u = u & 0xffff0000u; return v.f;
}
#if __has_builtin(__builtin_amdgcn_cvt_pk_bf16_f32)
typedef __attribute__((ext_vector_type(2))) __bf16 bf16x2_t;
static __device__ __forceinline__ uint32_t pk2(float lo, float hi) {
    union { bf16x2_t v; uint32_t u; } c;
    c.v = __builtin_amdgcn_cvt_pk_bf16_f32(lo, hi);
    return c.u;
}
static __device__ __forceinline__ unsigned short bf1(float v) {
    union { bf16x2_t v; uint32_t u; } c;
    c.v = __builtin_amdgcn_cvt_pk_bf16_f32(v, v);
    return (unsigned short)(c.u & 0xffffu);
}
#else
static __device__ __forceinline__ uint32_t pk2(float lo, float hi) {
    return ((uint32_t)f2bf(hi) << 16) | (uint32_t)f2bf(lo);
}
static __device__ __forceinline__ unsigned short bf1(float v) { return f2bf(v); }
#endif
static __device__ __forceinline__ short8 frag8(const float* p) {
    short8 r;
#pragma unroll
    for (int j = 0; j < 8; ++j) r[j] = (short)f2bf(p[j]);
    return r;
}

// LDS-only barrier: global stores/loads stay in flight across it.
static __device__ __forceinline__ void barrier_lds() {
    asm volatile("s_waitcnt lgkmcnt(0)" ::: "memory");
    __builtin_amdgcn_s_barrier();
}

// =====================================================================
// kernel 1: fused inp-gen + gates + chunked scan (R21 shape, proven).
// 512 thr = 8 waves. Scan: lane = h (64), wave q owns 16-l chunk.
// Gen GEMMs: wave (mq=q>>1, nh=q&1) owns 2 m-tiles x 2 n-tiles.
//   alpha { OUT(i-1) | GATES(i) }
//   beta  { t-load(i+1) | scanAB(i) | G1(i+1) [te1 from s_wb] }
//   gamma { x-load(i+1) | carry(i) | G2(i+1) }
// =====================================================================
#define SSTR 129

__global__ __launch_bounds__(512) void scan_fused(
    const float* __restrict__ x, const float* __restrict__ t,
    const float* __restrict__ mtok,
    const float* __restrict__ te_w1, const float* __restrict__ te_b1,
    const float* __restrict__ te_w2, const float* __restrict__ te_b2,
    const float* __restrict__ fpw, const float* __restrict__ fpb,
    const float* __restrict__ bpw, const float* __restrict__ bpb,
    const float* __restrict__ fwz, const float* __restrict__ fbz,
    const float* __restrict__ fwh, const float* __restrict__ fbh,
    const float* __restrict__ bwz, const float* __restrict__ bbz,
    const float* __restrict__ bwh, const float* __restrict__ bbh,
    int b0,
    unsigned short* __restrict__ hf, unsigned short* __restrict__ hb)
{
    __shared__ __align__(16) unsigned short s_tenc[128*72];  // 18432 B
    __shared__ __align__(16) unsigned short s_inp[128*72];   // 18432 B
    __shared__ uint32_t s_seg[64*SSTR];                      // 33024 B
    __shared__ float s_A[8][65], s_B[8][65];                 //  4160 B
    __shared__ float s_H[64];                                //   256 B
    __shared__ float2 s_wb[64];                              //   512 B

    const int rl  = blockIdx.x >> 1;
    const int dir = blockIdx.x & 1;
    const int tid = threadIdx.x;
    const int h   = tid & 63;     // lane
    const int q   = tid >> 6;     // wave 0..7
    const int lq  = h >> 4;
    const int ln  = h & 15;
    const int mq  = q >> 1;       // m-tile pair owner (0..3)
    const int nh  = q & 1;        // n-tile pair owner (0..1)

    const int gx = (b0 + rl) << 11;     // global l base for this b
    unsigned short* out = (dir ? hb : hf) + (size_t)rl * NL * 64;

    // ---- weights (persistent regs, nt-split: this wave's 2 n-tiles) ----
    short8 bte[2][2];
    float bite[2];
#pragma unroll
    for (int ni = 0; ni < 2; ++ni) {
        const int nt = nh*2 + ni;
        const float* row = te_w2 + (nt*16 + ln)*64;
#pragma unroll
        for (int ks = 0; ks < 2; ++ks) bte[ni][ks] = frag8(row + lq*8 + ks*32);
        bite[ni] = te_b2[nt*16 + ln];
    }
    const float* PW = dir ? bpw : fpw;
    const float* PB = dir ? bpb : fpb;
    short8 bpj[2][3];
    float bipj[2];
#pragma unroll
    for (int ni = 0; ni < 2; ++ni) {
        const int nt = nh*2 + ni;
        const float* row = PW + (nt*16 + ln)*67;
#pragma unroll
        for (int ks = 0; ks < 2; ++ks) {
            float tmp[8];
#pragma unroll
            for (int j = 0; j < 8; ++j) tmp[j] = row[3 + lq*8 + ks*32 + j];
            bpj[ni][ks] = frag8(tmp);
        }
        {
            float tmp[8];
#pragma unroll
            for (int j = 0; j < 8; ++j) tmp[j] = (lq == 0 && j < 3) ? row[j] : 0.f;
            bpj[ni][2] = frag8(tmp);
        }
        bipj[ni] = PB[nt*16 + ln];
    }
    const float* WZ = dir ? bwz : fwz;
    const float* WH = dir ? bwh : fwh;
    const float* BZ = dir ? bbz : fbz;
    const float* BH = dir ? bbh : fbh;
    short8 bz[2][2], bh[2][2];
    float biz[2], bih[2];
#pragma unroll
    for (int ni = 0; ni < 2; ++ni) {
        const int nt = nh*2 + ni;
        const float* rz = WZ + (nt*16 + ln)*64;
        const float* rh = WH + (nt*16 + ln)*64;
#pragma unroll
        for (int ks = 0; ks < 2; ++ks) {
            bz[ni][ks] = frag8(rz + lq*8 + ks*32);
            bh[ni][ks] = frag8(rh + lq*8 + ks*32);
        }
        biz[ni] = BZ[nt*16 + ln];
        bih[ni] = BH[nt*16 + ln];
    }
    const float mt0 = mtok[0], mt1 = mtok[1];

    // ---- phase lambdas ----
    auto G1 = [&](const float* tvv) {  // te1 from s_wb -> tenc GEMM
#pragma unroll
        for (int mi = 0; mi < 2; ++mi) {
            short8 a0, a1;
#pragma unroll
            for (int j = 0; j < 8; ++j) {
                const float2 wb0 = s_wb[lq*8 + j];
                const float2 wb1 = s_wb[lq*8 + 32 + j];
                a0[j] = (short)bf1(fmaxf(fmaf(tvv[mi], wb0.x, wb0.y), 0.f));
                a1[j] = (short)bf1(fmaxf(fmaf(tvv[mi], wb1.x, wb1.y), 0.f));
            }
#pragma unroll
            for (int ni = 0; ni < 2; ++ni) {
                f32x4 c = {0.f, 0.f, 0.f, 0.f};
                c = MFMA16(a0, bte[ni][0], c);
                c = MFMA16(a1, bte[ni][1], c);
                const int o = (nh*2+ni)*16 + ln;
#pragma unroll
                for (int r = 0; r < 4; ++r)
                    s_tenc[((mq*2+mi)*16 + lq*4 + r)*72 + o] = bf1(c[r] + bite[ni]);
            }
        }
    };
    auto G2 = [&](const float* xr0_, const float* xr1_, const float* xmc_) {
#pragma unroll
        for (int mi = 0; mi < 2; ++mi) {
            const int mrow = (mq*2+mi)*16 + ln;
            const short8 a0 = *(const short8*)(s_tenc + mrow*72 + lq*8);
            const short8 a1 = *(const short8*)(s_tenc + mrow*72 + lq*8 + 32);
            short8 a2 = {0,0,0,0,0,0,0,0};
            if (lq == 0) {
                const float mc  = xmc_[mi];
                const float x0m = (mc == 0.f) ? mt0 : xr0_[mi];
                const float x1m = (mc == 0.f) ? mt1 : xr1_[mi];
                a2[0] = (short)bf1(x0m);
                a2[1] = (short)bf1(x1m);
                a2[2] = (short)bf1(mc);
            }
#pragma unroll
            for (int ni = 0; ni < 2; ++ni) {
                f32x4 c = {0.f, 0.f, 0.f, 0.f};
                c = MFMA16(a0, bpj[ni][0], c);
                c = MFMA16(a1, bpj[ni][1], c);
                c = MFMA16(a2, bpj[ni][2], c);
                const int o = (nh*2+ni)*16 + ln;
#pragma unroll
                for (int r = 0; r < 4; ++r)
                    s_inp[((mq*2+mi)*16 + lq*4 + r)*72 + o] = bf1(c[r] + bipj[ni]);
            }
        }
    };
    auto GATES = [&]() {        // s_inp -> gates -> s_seg
#pragma unroll
        for (int mi = 0; mi < 2; ++mi) {
            const int mrow = (mq*2+mi)*16 + ln;
            const short8 a0 = *(const short8*)(s_inp + mrow*72 + lq*8);
            const short8 a1 = *(const short8*)(s_inp + mrow*72 + lq*8 + 32);
#pragma unroll
            for (int ni = 0; ni < 2; ++ni) {
                f32x4 cz  = {0.f, 0.f, 0.f, 0.f};
                f32x4 ch2 = {0.f, 0.f, 0.f, 0.f};
                cz  = MFMA16(a0, bz[ni][0], cz);
                cz  = MFMA16(a1, bz[ni][1], cz);
                ch2 = MFMA16(a0, bh[ni][0], ch2);
                ch2 = MFMA16(a1, bh[ni][1], ch2);
                const int hcol = (nh*2+ni)*16 + ln;
#pragma unroll
                for (int r = 0; r < 4; ++r) {
                    const float az = cz[r]  + biz[ni];
                    const float ah = ch2[r] + bih[ni];
                    const float z  = __builtin_amdgcn_rcpf(1.f + __expf(-az));
                    const float cc = fminf(fmaxf(ah, -15.f), 15.f);
                    const float e2 = __expf(2.f * cc);
                    const float th = 1.f - 2.f * __builtin_amdgcn_rcpf(e2 + 1.f);
                    s_seg[hcol*SSTR + (mq*2+mi)*16 + lq*4 + r] = pk2(1.f - z, z * th);
                }
            }
        }
    };

    if (tid < 64) {
        s_H[tid] = 0.f;
        s_wb[tid] = make_float2(te_w1[tid], te_b1[tid]);
    }
    barrier_lds();              // s_wb visible to all waves

    // ---- prologue: fill pipeline for segment s0 ----
    const int s0 = dir ? 15 : 0;
    {
        float tv0[2];
#pragma unroll
        for (int mi = 0; mi < 2; ++mi)
            tv0[mi] = t[gx + s0*128 + (mq*2+mi)*16 + ln];
        G1(tv0);               // seg s0 -> s_tenc
    }
    barrier_lds();
    {
        float xr0_[2], xr1_[2], xmc_[2];
        if (lq == 0) {
#pragma unroll
            for (int mi = 0; mi < 2; ++mi) {
                const float* xp = x + (size_t)(gx + s0*128 + (mq*2+mi)*16 + ln)*3;
                xr0_[mi] = xp[0]; xr1_[mi] = xp[1]; xmc_[mi] = xp[2];
            }
        }
        G2(xr0_, xr1_, xmc_);  // seg s0 -> s_inp
    }
    barrier_lds();

    uint32_t regs[16];
    int l0p = 0;

#pragma unroll 1
    for (int si = 0; si < 16; ++si) {
        const int s = dir ? (15 - si) : si;
        const int sn = dir ? (14 - si) : (si + 1);   // next segment (if any)
        // ---- alpha: OUT(prev) + GATES(cur) ----
        if (si > 0) {
            float hv = s_A[q][h];     // Hin written in-place by carry
#pragma unroll
            for (int i = 0; i < 16; ++i) {
                const int g = q*16 + i;
                const int xx = dir ? (127 - g) : g;
                out[(size_t)(l0p + xx)*64 + h] = bf1(hv);
                hv = fmaf(bflo(regs[i]), hv, bfhi(regs[i]));
            }
        }
        GATES();
        barrier_lds();
        // ---- beta: t-load(next) | scanAB(cur) | G1(next) ----
        float tvn[2];
        if (si < 15) {
#pragma unroll
            for (int mi = 0; mi < 2; ++mi)
                tvn[mi] = t[gx + sn*128 + (mq*2+mi)*16 + ln];
        }
        {
            float A = 1.f, Bc = 0.f;
#pragma unroll
            for (int i = 0; i < 16; ++i) {
                const int g = q*16 + i;
                const int xx = dir ? (127 - g) : g;
                const uint32_t uab = s_seg[h*SSTR + xx];
                regs[i] = uab;
                Bc = fmaf(bflo(uab), Bc, bfhi(uab));
                A *= bflo(uab);
            }
            s_A[q][h] = A; s_B[q][h] = Bc;
        }
        if (si < 15) G1(tvn);
        barrier_lds();
        // ---- gamma: x-load(next) | carry(cur) | G2(next) ----
        float xr0_[2], xr1_[2], xmc_[2];
        if (si < 15 && lq == 0) {
#pragma unroll
            for (int mi = 0; mi < 2; ++mi) {
                const float* xp = x + (size_t)(gx + sn*128 + (mq*2+mi)*16 + ln)*3;
                xr0_[mi] = xp[0]; xr1_[mi] = xp[1]; xmc_[mi] = xp[2];
            }
        }
        if (tid < 64) {
            float H = s_H[tid];
#pragma unroll
            for (int qq = 0; qq < 8; ++qq) {
                const float a = s_A[qq][tid], b = s_B[qq][tid];
                s_A[qq][tid] = H;          // in-place Hin
                H = fmaf(a, H, b);
            }
            s_H[tid] = H;
        }
        if (si < 15) G2(xr0_, xr1_, xmc_);
        barrier_lds();
        l0p = s * 128;
    }
    // ---- epilogue: OUT(last) ----
    {
        float hv = s_A[q][h];
#pragma unroll
        for (int i = 0; i < 16; ++i) {
            const int g = q*16 + i;
            const int xx = dir ? (127 - g) : g;
            out[(size_t)(l0p + xx)*64 + h] = bf1(hv);
            hv = fmaf(bflo(regs[i]), hv, bfhi(regs[i]));
        }
    }
}

// =====================================================================
// kernel 2: MFMA head — R24: async gather + in-reg te1 + hoisted mc.
// Per chunk (2 barriers):
//   A { Dp(prev) | TENC(ch) [in-reg te1 -> s_a cols 128..191]
//       | GWRITE(ch) [vmcnt-wait + ds_write gather regs -> s_a 0..127] }
//   B { GISSUE(ch+1) [global loads -> regs, in flight] | Cp(ch) }
// =====================================================================
__global__ __launch_bounds__(256, 3) void head_kernel(
    const float* __restrict__ x, const float* __restrict__ t,
    const float* __restrict__ te_w1, const float* __restrict__ te_b1,
    const float* __restrict__ te_w2, const float* __restrict__ te_b2,
    const unsigned short* __restrict__ hf, const unsigned short* __restrict__ hb,
    const float* __restrict__ w1, const float* __restrict__ b1,
    const float* __restrict__ w2, const float* __restrict__ b2,
    int b0,
    float* __restrict__ out)
{
    __shared__ __align__(16) unsigned short s_a[64*200];   // 25600 B
    __shared__ float s_part[4][64];                        //  1024 B
    __shared__ float s_mcall[256];                         //  1024 B
    __shared__ float2 s_wb[64];                            //   512 B
    // total 28160 B

    const int tid = threadIdx.x;
    const int w   = tid >> 6;
    const int l   = tid & 63;
    const int lq  = l >> 4;
    const int ln  = l & 15;

    short8 bw1[2][6];
    float b1v[2], w2v[2];
#pragma unroll
    for (int p = 0; p < 2; ++p) {
        const int o = (2*w + p)*16 + ln;
        const float* row = w1 + o*192;
#pragma unroll
        for (int ks = 0; ks < 6; ++ks) bw1[p][ks] = frag8(row + lq*8 + ks*32);
        b1v[p] = b1[o];
        w2v[p] = w2[o];
    }
    short8 bte[2];
    {
        const float* row = te_w2 + (w*16 + ln)*64;
#pragma unroll
        for (int ks = 0; ks < 2; ++ks) bte[ks] = frag8(row + lq*8 + ks*32);
    }
    const float bias_te = te_b2[w*16 + ln];
    const float bias2 = b2[0];

    const int baseposl = blockIdx.x * 256;
    const int gbase0 = (b0 << 11) + baseposl;

    uint4 greg[4];              // in-flight gather (next chunk)

    auto GISSUE = [&](int ch) { // issue 4 uint4 loads -> greg
        const int chbase = baseposl + ch*64;
        const int ll0 = chbase & 2047;
        const int bl  = chbase >> 11;
        const size_t rowbase = (size_t)bl * NL * 64;
#pragma unroll
        for (int rep = 0; rep < 4; ++rep) {
            const int idx = rep*256 + tid;
            const int seg = idx >> 9;
            const int row = (idx >> 3) & 63;
            const int c   = idx & 7;
            const bool unm = s_mcall[ch*64 + row] > 0.f;
            const uint4* src = (seg == 0)
                ? (const uint4*)(hf + rowbase + (size_t)(unm ? (ll0+row) : (NL-1))*64)
                : (const uint4*)(hb + rowbase + (size_t)(unm ? (ll0+row) : 0)*64);
            greg[rep] = src[c];
        }
    };
    auto GWRITE = [&]() {       // greg -> s_a cols 0..127
#pragma unroll
        for (int rep = 0; rep < 4; ++rep) {
            const int idx = rep*256 + tid;
            const int seg = idx >> 9;
            const int row = (idx >> 3) & 63;
            const int c   = idx & 7;
            ((uint4*)s_a)[row*25 + seg*8 + c] = greg[rep];
        }
    };
    auto TENC = [&](int ch) {   // in-reg te1 -> tenc GEMM -> s_a cols 128..191
        const int chbase = gbase0 + ch*64;
        const int o = w*16 + ln;
#pragma unroll
        for (int mt = 0; mt < 4; ++mt) {
            const float tv = t[chbase + mt*16 + ln];
            short8 a0, a1;
#pragma unroll
            for (int j = 0; j < 8; ++j) {
                const float2 wb0 = s_wb[lq*8 + j];
                const float2 wb1 = s_wb[lq*8 + 32 + j];
                a0[j] = (short)bf1(fmaxf(fmaf(tv, wb0.x, wb0.y), 0.f));
                a1[j] = (short)bf1(fmaxf(fmaf(tv, wb1.x, wb1.y), 0.f));
            }
            f32x4 c = {0.f, 0.f, 0.f, 0.f};
            c = MFMA16(a0, bte[0], c);
            c = MFMA16(a1, bte[1], c);
#pragma unroll
            for (int r = 0; r < 4; ++r)
                s_a[(mt*16 + lq*4 + r)*200 + 128 + o] = bf1(c[r] + bias_te);
        }
    };
    auto Cp = [&]() {           // GEMM1 + relu*w2 + quad shuffle-reduce
#pragma unroll
        for (int mt = 0; mt < 4; ++mt) {
            short8 af[6];
#pragma unroll
            for (int ks = 0; ks < 6; ++ks)
                af[ks] = *(const short8*)(s_a + (mt*16+ln)*200 + lq*8 + ks*32);
            float vs[4] = {0.f, 0.f, 0.f, 0.f};
#pragma unroll
            for (int p = 0; p < 2; ++p) {
                f32x4 c = {0.f, 0.f, 0.f, 0.f};
#pragma unroll
                for (int ks = 0; ks < 6; ++ks) c = MFMA16(af[ks], bw1[p][ks], c);
#pragma unroll
                for (int r = 0; r < 4; ++r)
                    vs[r] += fmaxf(c[r] + b1v[p], 0.f) * w2v[p];
            }
#pragma unroll
            for (int mask = 1; mask < 16; mask <<= 1) {
#pragma unroll
                for (int r = 0; r < 4; ++r)
                    vs[r] += __shfl_xor(vs[r], mask);
            }
            if (ln == 0) {
#pragma unroll
                for (int r = 0; r < 4; ++r)
                    s_part[w][mt*16 + lq*4 + r] = vs[r];
            }
        }
    };
    auto Dp = [&](int ch) {     // out write (reads s_part)
        if (tid < 64) {
            out[gbase0 + ch*64 + tid] = s_part[0][tid] + s_part[1][tid]
                                      + s_part[2][tid] + s_part[3][tid] + bias2;
        }
    };

    // ---- prologue: mc for all 4 chunks + te table, then first gather ----
    s_mcall[tid] = x[(size_t)(gbase0 + tid)*3 + 2];
    if (tid < 64) s_wb[tid] = make_float2(te_w1[tid], te_b1[tid]);
    barrier_lds();
    GISSUE(0);

#pragma unroll 1
    for (int ch = 0; ch < 4; ++ch) {
        if (ch > 0) Dp(ch - 1);      // reads s_part (barriered in prev iter)
        TENC(ch);                    // writes s_a cols 128..191
        GWRITE();                    // vmcnt-wait greg, writes s_a cols 0..127
        barrier_lds();
        if (ch < 3) GISSUE(ch + 1);  // loads in flight under Cp
        Cp();
        barrier_lds();
    }
    Dp(3);
}

extern "C" void kernel_launch(void* const* d_in, const int* in_sizes, int n_in,
                              void* d_out, int out_size, void* d_ws, size_t ws_size,
                              hipStream_t stream)
{
    const float* x     = (const float*)d_in[0];
    const float* t     = (const float*)d_in[1];
    const float* mtok  = (const float*)d_in[2];
    const float* te_w1 = (const float*)d_in[3];
    const float* te_b1 = (const float*)d_in[4];
    const float* te_w2 = (const float*)d_in[5];
    const float* te_b2 = (const float*)d_in[6];
    const float* fpw   = (const float*)d_in[7];
    const float* fpb   = (const float*)d_in[8];
    const float* bpw   = (const float*)d_in[9];
    const float* bpb   = (const float*)d_in[10];
    const float* fwz   = (const float*)d_in[11];
    const float* fbz   = (const float*)d_in[12];
    const float* fwh   = (const float*)d_in[13];
    const float* fbh   = (const float*)d_in[14];
    const float* bwz   = (const float*)d_in[15];
    const float* bbz   = (const float*)d_in[16];
    const float* bwh   = (const float*)d_in[17];
    const float* bbh   = (const float*)d_in[18];
    const float* w1    = (const float*)d_in[19];
    const float* b1    = (const float*)d_in[20];
    const float* w2    = (const float*)d_in[21];
    const float* b2    = (const float*)d_in[22];

    // per b: h (2 dirs) = 512 KB
    const size_t per_b = 524288ull;
    int Bg = NB;
    while ((size_t)Bg * per_b > ws_size && Bg > 1) Bg >>= 1;
    const int nG = NB / Bg;

    char* ws = (char*)d_ws;
    unsigned short* hf = (unsigned short*)ws;
    unsigned short* hb = hf + (size_t)Bg * NL * 64;

    for (int g = 0; g < nG; ++g) {
        const int b0 = g * Bg;

        scan_fused<<<2 * Bg, 512, 0, stream>>>(
            x, t, mtok, te_w1, te_b1, te_w2, te_b2,
            fpw, fpb, bpw, bpb, fwz, fbz, fwh, fbh, bwz, bbz, bwh, bbh,
            b0, hf, hb);

        head_kernel<<<8 * Bg, 256, 0, stream>>>(
            x, t, te_w1, te_b1, te_w2, te_b2,
            hf, hb, w1, b1, w2, b2, b0, (float*)d_out);
    }
}